// Round 22
// baseline (714.832 us; speedup 1.0000x reference)
//
#include <hip/hip_runtime.h>
#include <hip/hip_bf16.h>

// MultiLoRALinear: out = x@W.T + bias + (x @ A[idx]) @ B[idx]
// M=16384, K=4096, N=4096, rank 16.
//
// R22 = R21's 8-phase structure with RACE-FREE staging.
// R21 failed (absmax 3.75): it staged tile t+2 into buf[t&1] while tile t's
// waves were still reading it (barrier skew). Fix: stage tile t+1 into the
// OTHER buffer (buf^1), all 8 loads front-loaded in P1 (3 phases ~1500cyc of
// slack > ~900cyc HBM latency), vmcnt(0) before tile t's final barrier.
// Audit: buf[t&1] re-staged only in t+1's P1, after all its reads drained
// (per-phase lgkm0 + final barrier). No buffer written while readable.
// R22 vs R15 = clean A/B of per-phase fragment-read batching with 2 barriers
// per phase (m196's lever) vs whole-tile reads.
//  - Per K-tile 4 phases: P1 {12 reads (8 B + A mf0-1), stage 8 loads(t+1),
//    lgkm(8), bar, lgkm0, 16 MFMA, bar}; P2-P4 {4 A-reads, bar, lgkm0,
//    16 MFMA, [P4: vmcnt(0)], bar}.
//  - R15 conflict-free swizzle; R10 epilogue; R20 fused pre-pass.

#define M_TOT 16384
#define K_TOT 4096
#define N_TOT 4096
#define RANK 16

typedef __attribute__((ext_vector_type(8))) short bf16x8;
typedef __attribute__((ext_vector_type(4))) float f32x4;

// ---------------- fp32 -> bf16 (round-to-nearest-even) ----------------
__device__ __forceinline__ unsigned short f2bf(float f) {
  unsigned int u = __builtin_bit_cast(unsigned int, f);
  u += 0x7fffu + ((u >> 16) & 1u);
  return (unsigned short)(u >> 16);
}

__global__ void cvt_bf16_kernel(const float* __restrict__ src,
                                unsigned short* __restrict__ dst, int n4) {
  int i = blockIdx.x * blockDim.x + threadIdx.x;
  const int stride = gridDim.x * blockDim.x;
  for (; i < n4; i += stride) {
    const float4 v = reinterpret_cast<const float4*>(src)[i];
    ushort4 o;
    o.x = f2bf(v.x); o.y = f2bf(v.y); o.z = f2bf(v.z); o.w = f2bf(v.w);
    reinterpret_cast<ushort4*>(dst)[i] = o;
  }
}

// ---- fused: xb = bf16(x) AND inter = x @ A[slot]; 4 waves split K (R20) ----
__global__ __launch_bounds__(256) void fused_xcvt_inter_kernel(
    const float* __restrict__ x,
    const float* __restrict__ loraA,
    const int* __restrict__ idx,
    unsigned short* __restrict__ xb,
    float* __restrict__ inter) {
  __shared__ float red[4][16][17];
  const int lane = threadIdx.x & 63;
  const int wq = threadIdx.x >> 6;
  const int m0 = blockIdx.x * 16;
  const int slot = idx[m0 >> 11];
  const int q = lane >> 4;
  const int c = lane & 15;
  const int k0 = wq * 1024;
  const float* __restrict__ xrow = x + (size_t)(m0 + c) * K_TOT + k0 + q * 8;
  unsigned short* __restrict__ xbrow = xb + (size_t)(m0 + c) * K_TOT + k0 + q * 8;
  const float* __restrict__ Abase = loraA + (size_t)slot * K_TOT * RANK + c;

  f32x4 acc = (f32x4){0.f, 0.f, 0.f, 0.f};
#pragma unroll 4
  for (int kt = 0; kt < 1024; kt += 32) {
    const float4 xv0 = *reinterpret_cast<const float4*>(xrow + kt);
    const float4 xv1 = *reinterpret_cast<const float4*>(xrow + kt + 4);
    bf16x8 af;
    af[0] = (short)f2bf(xv0.x); af[1] = (short)f2bf(xv0.y);
    af[2] = (short)f2bf(xv0.z); af[3] = (short)f2bf(xv0.w);
    af[4] = (short)f2bf(xv1.x); af[5] = (short)f2bf(xv1.y);
    af[6] = (short)f2bf(xv1.z); af[7] = (short)f2bf(xv1.w);
    *reinterpret_cast<bf16x8*>(xbrow + kt) = af;
    const float* __restrict__ Ak = Abase + (size_t)(k0 + kt + q * 8) * RANK;
    bf16x8 bfr;
#pragma unroll
    for (int j = 0; j < 8; ++j) bfr[j] = (short)f2bf(Ak[(size_t)j * RANK]);
    acc = __builtin_amdgcn_mfma_f32_16x16x32_bf16(af, bfr, acc, 0, 0, 0);
  }
#pragma unroll
  for (int i = 0; i < 4; ++i) red[wq][q * 4 + i][c] = acc[i];
  __syncthreads();
  if (wq == 0) {
#pragma unroll
    for (int i = 0; i < 4; ++i) {
      const int row = q * 4 + i;
      inter[(size_t)(m0 + row) * RANK + c] =
          red[0][row][c] + red[1][row][c] + red[2][row][c] + red[3][row][c];
    }
  }
}

// ---------------- 8-phase 256x256 GEMM, dbuf-2, race-free staging ----------
__device__ __forceinline__ void gload16(const void* g, void* l) {
  __builtin_amdgcn_global_load_lds(
      (const __attribute__((address_space(1))) unsigned int*)g,
      (__attribute__((address_space(3))) unsigned int*)l, 16, 0, 0);
}

#define GBARRIER() asm volatile("s_barrier" ::: "memory")
#define RD(p) (*reinterpret_cast<const bf16x8*>(p))

__global__ __launch_bounds__(512, 2) void gemm_fused_kernel(
    const unsigned short* __restrict__ xb,   // [M][K] bf16
    const unsigned short* __restrict__ wb,   // [N][K] bf16
    const float* __restrict__ bias,          // [N]
    const float* __restrict__ inter,         // [M][RANK] f32
    const float* __restrict__ loraB,         // [32][RANK][N] f32
    const int* __restrict__ idx,             // [8]
    float* __restrict__ out) {               // [M][N] f32
  __shared__ unsigned short lds[2][32768];
  char* ldsB = (char*)&lds[0][0];

  const int tid = threadIdx.x;
  const int lane = tid & 63;
  const int wv = tid >> 6;
  const int wr = wv >> 2;
  const int wc = wv & 3;

  const int bid = ((blockIdx.x & 7) << 7) | (blockIdx.x >> 3);
  const int m0 = (bid >> 4) << 8;
  const int n0 = (bid & 15) << 8;

  const int r0 = tid >> 3;
  const int scol = ((tid & 7) ^ (r0 & 7)) << 3;
  const unsigned short* xsrc = xb + (size_t)(m0 + r0) * K_TOT + scol;
  const unsigned short* wsrc = wb + (size_t)(n0 + r0) * K_TOT + scol;
  const int stg = tid << 4;

#define STAGE_T(BOFS, KO)                                                     \
  do {                                                                        \
    gload16(xsrc + (KO),                        ldsB + (BOFS) + stg);         \
    gload16(xsrc + (size_t)64  * K_TOT + (KO),  ldsB + (BOFS) + 8192 + stg);  \
    gload16(xsrc + (size_t)128 * K_TOT + (KO),  ldsB + (BOFS) + 16384 + stg); \
    gload16(xsrc + (size_t)192 * K_TOT + (KO),  ldsB + (BOFS) + 24576 + stg); \
    gload16(wsrc + (KO),                        ldsB + (BOFS) + 32768 + stg); \
    gload16(wsrc + (size_t)64  * K_TOT + (KO),  ldsB + (BOFS) + 40960 + stg); \
    gload16(wsrc + (size_t)128 * K_TOT + (KO),  ldsB + (BOFS) + 49152 + stg); \
    gload16(wsrc + (size_t)192 * K_TOT + (KO),  ldsB + (BOFS) + 57344 + stg); \
  } while (0)

  const int rl = lane & 15;
  const int q = lane >> 4;
  const int swz = rl & 7;
  const int aoff0 = (wr * 128 + rl) * 128 + ((q ^ swz) << 4);
  const int aoff1 = (wr * 128 + rl) * 128 + (((4 + q) ^ swz) << 4);
  const int boff0 = 32768 + (wc * 64 + rl) * 128 + ((q ^ swz) << 4);
  const int boff1 = 32768 + (wc * 64 + rl) * 128 + (((4 + q) ^ swz) << 4);

  f32x4 acc[8][4];
#pragma unroll
  for (int i = 0; i < 8; ++i)
#pragma unroll
    for (int j = 0; j < 4; ++j) acc[i][j] = (f32x4){0.f, 0.f, 0.f, 0.f};

  bf16x8 bfr0[4], bfr1[4], afr[4];

#define PH_MFMA(MF)                                                        \
  do {                                                                     \
    _Pragma("unroll")                                                      \
    for (int nf = 0; nf < 4; ++nf) {                                       \
      acc[(MF)][nf] = __builtin_amdgcn_mfma_f32_16x16x32_bf16(             \
          afr[0], bfr0[nf], acc[(MF)][nf], 0, 0, 0);                       \
      acc[(MF)][nf] = __builtin_amdgcn_mfma_f32_16x16x32_bf16(             \
          afr[1], bfr1[nf], acc[(MF)][nf], 0, 0, 0);                       \
      acc[(MF) + 1][nf] = __builtin_amdgcn_mfma_f32_16x16x32_bf16(         \
          afr[2], bfr0[nf], acc[(MF) + 1][nf], 0, 0, 0);                   \
      acc[(MF) + 1][nf] = __builtin_amdgcn_mfma_f32_16x16x32_bf16(         \
          afr[3], bfr1[nf], acc[(MF) + 1][nf], 0, 0, 0);                   \
    }                                                                      \
  } while (0)

  // ---- prologue: stage tile 0 -> buf0, drain, barrier ----
  STAGE_T(0, 0);
  asm volatile("s_waitcnt vmcnt(0)" ::: "memory");
  GBARRIER();

#pragma unroll 1
  for (int t = 0; t < 64; ++t) {
    const int bofs = (t & 1) << 16;
    const int nbofs = ((t + 1) & 1) << 16;
    const size_t ko = (size_t)(t + 1) * 64;
    const bool st = t < 63;

    // ---- P1: 12 reads (8 B + A mf0-1); stage ALL of tile t+1 -> buf^1 ----
#pragma unroll
    for (int nf = 0; nf < 4; ++nf) bfr0[nf] = RD(ldsB + bofs + boff0 + nf * 2048);
#pragma unroll
    for (int nf = 0; nf < 4; ++nf) bfr1[nf] = RD(ldsB + bofs + boff1 + nf * 2048);
    afr[0] = RD(ldsB + bofs + aoff0);
    afr[1] = RD(ldsB + bofs + aoff1);
    afr[2] = RD(ldsB + bofs + aoff0 + 2048);
    afr[3] = RD(ldsB + bofs + aoff1 + 2048);
    if (st) STAGE_T(nbofs, ko);
    asm volatile("s_waitcnt lgkmcnt(8)" ::: "memory");
    GBARRIER();
    asm volatile("s_waitcnt lgkmcnt(0)" ::: "memory");
    __builtin_amdgcn_sched_barrier(0);
    __builtin_amdgcn_s_setprio(1);
    PH_MFMA(0);
    __builtin_amdgcn_s_setprio(0);
    __builtin_amdgcn_sched_barrier(0);
    GBARRIER();

    // ---- P2..P4: 4 A-reads each; 16 MFMA; P4 adds vmcnt(0) ----
#pragma unroll
    for (int ph = 1; ph < 4; ++ph) {
      const int mf = 2 * ph;
      afr[0] = RD(ldsB + bofs + aoff0 + mf * 2048);
      afr[1] = RD(ldsB + bofs + aoff1 + mf * 2048);
      afr[2] = RD(ldsB + bofs + aoff0 + (mf + 1) * 2048);
      afr[3] = RD(ldsB + bofs + aoff1 + (mf + 1) * 2048);
      GBARRIER();
      asm volatile("s_waitcnt lgkmcnt(0)" ::: "memory");
      __builtin_amdgcn_sched_barrier(0);
      __builtin_amdgcn_s_setprio(1);
      PH_MFMA(mf);
      __builtin_amdgcn_s_setprio(0);
      __builtin_amdgcn_sched_barrier(0);
      if (ph == 3) {
        asm volatile("s_waitcnt vmcnt(0)" ::: "memory");
      }
      GBARRIER();
    }
  }

  // ------------- epilogue (R10 structure): + bias + inter @ B[slot] -------------
  const int slot = idx[m0 >> 11];
  const float* __restrict__ Bmat = loraB + (size_t)slot * RANK * N_TOT;
  const int gn0 = n0 + wc * 64 + rl;

  float bcv[4][RANK];
  float bv[4];
#pragma unroll
  for (int nf = 0; nf < 4; ++nf) {
    const int gn = gn0 + nf * 16;
    bv[nf] = bias[gn];
#pragma unroll
    for (int p = 0; p < RANK; ++p) bcv[nf][p] = Bmat[(size_t)p * N_TOT + gn];
  }
#pragma unroll
  for (int mf = 0; mf < 8; ++mf) {
    const int gmb = m0 + wr * 128 + mf * 16 + (q << 2);
#pragma unroll
    for (int r = 0; r < 4; ++r) {
      const int gm = gmb + r;
      const float4* ivp = reinterpret_cast<const float4*>(inter + (size_t)gm * RANK);
      const float4 iv0 = ivp[0], iv1 = ivp[1], iv2 = ivp[2], iv3 = ivp[3];
      float* orow = out + (size_t)gm * N_TOT;
#pragma unroll
      for (int nf = 0; nf < 4; ++nf) {
        const float lora =
            iv0.x * bcv[nf][0]  + iv0.y * bcv[nf][1]  + iv0.z * bcv[nf][2]  + iv0.w * bcv[nf][3] +
            iv1.x * bcv[nf][4]  + iv1.y * bcv[nf][5]  + iv1.z * bcv[nf][6]  + iv1.w * bcv[nf][7] +
            iv2.x * bcv[nf][8]  + iv2.y * bcv[nf][9]  + iv2.z * bcv[nf][10] + iv2.w * bcv[nf][11] +
            iv3.x * bcv[nf][12] + iv3.y * bcv[nf][13] + iv3.z * bcv[nf][14] + iv3.w * bcv[nf][15];
        orow[gn0 + nf * 16] = acc[mf][nf][r] + bv[nf] + lora;
      }
    }
  }
#undef STAGE_T
#undef PH_MFMA
}

// ---------------- host launcher ----------------
extern "C" void kernel_launch(void* const* d_in, const int* in_sizes, int n_in,
                              void* d_out, int out_size, void* d_ws, size_t ws_size,
                              hipStream_t stream) {
  const float* x     = (const float*)d_in[0];  // [8,2048,4096]
  const float* w     = (const float*)d_in[1];  // [4096,4096]
  const float* bias  = (const float*)d_in[2];  // [4096]
  const float* loraA = (const float*)d_in[3];  // [32,4096,16]
  const float* loraB = (const float*)d_in[4];  // [32,16,4096]
  const int*   idx   = (const int*)d_in[5];    // [8]
  float* out = (float*)d_out;

  char* ws = (char*)d_ws;
  unsigned short* xb   = (unsigned short*)ws;                  // 134,217,728 B
  unsigned short* wbuf = (unsigned short*)(ws + 134217728);    //  33,554,432 B
  float* inter = (float*)(ws + 134217728 + 33554432);          //   1,048,576 B

  fused_xcvt_inter_kernel<<<M_TOT / 16, 256, 0, stream>>>(x, loraA, idx, xb, inter);
  cvt_bf16_kernel<<<1024, 256, 0, stream>>>(w, wbuf, N_TOT * K_TOT / 4);
  gemm_fused_kernel<<<(M_TOT / 256) * (N_TOT / 256), 512, 0, stream>>>(
      xb, wbuf, bias, inter, loraB, idx, out);
}

// Round 23
// 643.035 us; speedup vs baseline: 1.1117x; 1.1117x over previous
//
#include <hip/hip_runtime.h>
#include <hip/hip_bf16.h>

// MultiLoRALinear: out = x@W.T + bias + (x @ A[idx]) @ B[idx]
// M=16384, K=4096, N=4096, rank 16.
//
// R23 = R20 restored verbatim (best measured config: 643.6us total).
// Session evidence (9 GEMM structures): R15/R20's BK=64 dbuf-2, counted-lgkm,
// 1-barrier-per-tile schedule at 532-556us GEMM (990 TF, MfmaUtil 47%,
// 0 conflicts, no spill) is the ceiling of this structure family from HIP
// source on this shape:
//  - more barriers/phases (R22 8-phase): 646us, 36.7% (barrier skew)
//  - fewer barriers (R11): 550us; deeper intra-tile ILP (R12): 536us
//  - 2x occupancy (R13): 561us; block antiphase (R14): 583us
//  - 32x32x16 MFMA: intrinsic read-shape bank conflict (R16/R17, bit-exact
//    5.03e7 under 2 permutations) or staging scatter (R18)
//  - m201 template ports: race (R21) / regression (R22) - m152's lesson.
// Pre-pass: fused cvt_x+inter (4 waves split K, LDS reduce) + cvt_w = ~87us.

#define M_TOT 16384
#define K_TOT 4096
#define N_TOT 4096
#define RANK 16
#define NT2 64   // K_TOT / 64

typedef __attribute__((ext_vector_type(8))) short bf16x8;
typedef __attribute__((ext_vector_type(4))) float f32x4;

// ---------------- fp32 -> bf16 (round-to-nearest-even) ----------------
__device__ __forceinline__ unsigned short f2bf(float f) {
  unsigned int u = __builtin_bit_cast(unsigned int, f);
  u += 0x7fffu + ((u >> 16) & 1u);
  return (unsigned short)(u >> 16);
}

__global__ void cvt_bf16_kernel(const float* __restrict__ src,
                                unsigned short* __restrict__ dst, int n4) {
  int i = blockIdx.x * blockDim.x + threadIdx.x;
  const int stride = gridDim.x * blockDim.x;
  for (; i < n4; i += stride) {
    const float4 v = reinterpret_cast<const float4*>(src)[i];
    ushort4 o;
    o.x = f2bf(v.x); o.y = f2bf(v.y); o.z = f2bf(v.z); o.w = f2bf(v.w);
    reinterpret_cast<ushort4*>(dst)[i] = o;
  }
}

// ---- fused: xb = bf16(x) AND inter = x @ A[slot]; 4 waves split K ----
__global__ __launch_bounds__(256) void fused_xcvt_inter_kernel(
    const float* __restrict__ x,
    const float* __restrict__ loraA,
    const int* __restrict__ idx,
    unsigned short* __restrict__ xb,
    float* __restrict__ inter) {
  __shared__ float red[4][16][17];   // [wave][row][r], padded
  const int lane = threadIdx.x & 63;
  const int wq = threadIdx.x >> 6;        // K-quarter 0..3
  const int m0 = blockIdx.x * 16;
  const int slot = idx[m0 >> 11];
  const int q = lane >> 4;
  const int c = lane & 15;
  const int k0 = wq * 1024;
  const float* __restrict__ xrow = x + (size_t)(m0 + c) * K_TOT + k0 + q * 8;
  unsigned short* __restrict__ xbrow = xb + (size_t)(m0 + c) * K_TOT + k0 + q * 8;
  const float* __restrict__ Abase = loraA + (size_t)slot * K_TOT * RANK + c;

  f32x4 acc = (f32x4){0.f, 0.f, 0.f, 0.f};
#pragma unroll 4
  for (int kt = 0; kt < 1024; kt += 32) {
    const float4 xv0 = *reinterpret_cast<const float4*>(xrow + kt);
    const float4 xv1 = *reinterpret_cast<const float4*>(xrow + kt + 4);
    bf16x8 af;
    af[0] = (short)f2bf(xv0.x); af[1] = (short)f2bf(xv0.y);
    af[2] = (short)f2bf(xv0.z); af[3] = (short)f2bf(xv0.w);
    af[4] = (short)f2bf(xv1.x); af[5] = (short)f2bf(xv1.y);
    af[6] = (short)f2bf(xv1.z); af[7] = (short)f2bf(xv1.w);
    *reinterpret_cast<bf16x8*>(xbrow + kt) = af;
    const float* __restrict__ Ak = Abase + (size_t)(k0 + kt + q * 8) * RANK;
    bf16x8 bfr;
#pragma unroll
    for (int j = 0; j < 8; ++j) bfr[j] = (short)f2bf(Ak[(size_t)j * RANK]);
    acc = __builtin_amdgcn_mfma_f32_16x16x32_bf16(af, bfr, acc, 0, 0, 0);
  }
  // C/D: col=c (r of inter), row=q*4+i (x-row within the 16)
#pragma unroll
  for (int i = 0; i < 4; ++i) red[wq][q * 4 + i][c] = acc[i];
  __syncthreads();
  if (wq == 0) {
#pragma unroll
    for (int i = 0; i < 4; ++i) {
      const int row = q * 4 + i;
      inter[(size_t)(m0 + row) * RANK + c] =
          red[0][row][c] + red[1][row][c] + red[2][row][c] + red[3][row][c];
    }
  }
}

// ---------------- BK=64 dbuf-2 256x256 GEMM, 8 waves (R15 verbatim) ----------
__device__ __forceinline__ void gload16(const void* g, void* l) {
  __builtin_amdgcn_global_load_lds(
      (const __attribute__((address_space(1))) unsigned int*)g,
      (__attribute__((address_space(3))) unsigned int*)l, 16, 0, 0);
}

#define GBARRIER() asm volatile("s_barrier" ::: "memory")
#define RD(p) (*reinterpret_cast<const bf16x8*>(p))

__global__ __launch_bounds__(512, 2) void gemm_fused_kernel(
    const unsigned short* __restrict__ xb,   // [M][K] bf16
    const unsigned short* __restrict__ wb,   // [N][K] bf16
    const float* __restrict__ bias,          // [N]
    const float* __restrict__ inter,         // [M][RANK] f32
    const float* __restrict__ loraB,         // [32][RANK][N] f32
    const int* __restrict__ idx,             // [8]
    float* __restrict__ out) {               // [M][N] f32
  // dbuf-2 x (A: 256x64 bf16 = 32KB @0, B: 32KB @32768) = 128 KiB
  __shared__ unsigned short lds[2][32768];
  char* ldsB = (char*)&lds[0][0];

  const int tid = threadIdx.x;
  const int lane = tid & 63;
  const int wv = tid >> 6;   // 0..7
  const int wr = wv >> 2;    // 0..1 (M half)
  const int wc = wv & 3;     // 0..3 (N quarter)

  // XCD-aware bijective swizzle: 1024 wgs, 8 XCDs, 128 per chunk
  const int bid = ((blockIdx.x & 7) << 7) | (blockIdx.x >> 3);
  const int m0 = (bid >> 4) << 8;   // 64 M-panels
  const int n0 = (bid & 15) << 8;   // 16 N-panels

  // ---- staging source (pre-permuted by the swizzle involution) ----
  const int r0 = tid >> 3;                              // 0..63
  const int scol = ((tid & 7) ^ (r0 & 7)) << 3;         // bf16 elems
  const unsigned short* xsrc = xb + (size_t)(m0 + r0) * K_TOT + scol;
  const unsigned short* wsrc = wb + (size_t)(n0 + r0) * K_TOT + scol;
  const int stg = tid << 4;

#define STAGE64(t)                                                       \
  do {                                                                   \
    const int _bo = (((t) & 1) << 16);                                   \
    const size_t _ko = (size_t)(t) * 64;                                 \
    gload16(xsrc + _ko,                        ldsB + _bo + stg);        \
    gload16(xsrc + (size_t)64  * K_TOT + _ko,  ldsB + _bo + 8192 + stg); \
    gload16(xsrc + (size_t)128 * K_TOT + _ko,  ldsB + _bo + 16384 + stg);\
    gload16(xsrc + (size_t)192 * K_TOT + _ko,  ldsB + _bo + 24576 + stg);\
    gload16(wsrc + _ko,                        ldsB + _bo + 32768 + stg);\
    gload16(wsrc + (size_t)64  * K_TOT + _ko,  ldsB + _bo + 40960 + stg);\
    gload16(wsrc + (size_t)128 * K_TOT + _ko,  ldsB + _bo + 49152 + stg);\
    gload16(wsrc + (size_t)192 * K_TOT + _ko,  ldsB + _bo + 57344 + stg);\
  } while (0)

  // ---- ds_read byte offsets: row stride 128B, phys_slot = slot ^ (row&7) ----
  const int rl = lane & 15;
  const int q = lane >> 4;
  const int swz = rl & 7;
  const int aoff0 = (wr * 128 + rl) * 128 + ((q ^ swz) << 4);          // kk0
  const int aoff1 = (wr * 128 + rl) * 128 + (((4 + q) ^ swz) << 4);    // kk1
  const int boff0 = 32768 + (wc * 64 + rl) * 128 + ((q ^ swz) << 4);
  const int boff1 = 32768 + (wc * 64 + rl) * 128 + (((4 + q) ^ swz) << 4);

  f32x4 acc[8][4];
#pragma unroll
  for (int i = 0; i < 8; ++i)
#pragma unroll
    for (int j = 0; j < 4; ++j) acc[i][j] = (f32x4){0.f, 0.f, 0.f, 0.f};

  // ---- prologue: stage tile 0, drain, barrier ----
  STAGE64(0);
  asm volatile("s_waitcnt vmcnt(0)" ::: "memory");
  GBARRIER();

#pragma unroll 1
  for (int t = 0; t < NT2; ++t) {
    const char* base = ldsB + ((t & 1) << 16);
    bf16x8 af[8], bfr0[4], bfr1[4];

    // issue kk0 reads (12) + kk1 B reads (4); then stage next tile
#pragma unroll
    for (int nf = 0; nf < 4; ++nf) bfr0[nf] = RD(base + boff0 + nf * 2048);
#pragma unroll
    for (int mf = 0; mf < 8; ++mf) af[mf] = RD(base + aoff0 + mf * 2048);
#pragma unroll
    for (int nf = 0; nf < 4; ++nf) bfr1[nf] = RD(base + boff1 + nf * 2048);
    if (t < NT2 - 1) STAGE64(t + 1);

    // wait kk0's 12 reads; bfr1's 4 stay in flight under MFMA-1
    asm volatile("s_waitcnt lgkmcnt(4)" ::: "memory");
    __builtin_amdgcn_sched_barrier(0);
    __builtin_amdgcn_s_setprio(1);
#pragma unroll
    for (int mf = 0; mf < 8; ++mf)
#pragma unroll
      for (int nf = 0; nf < 4; ++nf)
        acc[mf][nf] = __builtin_amdgcn_mfma_f32_16x16x32_bf16(
            af[mf], bfr0[nf], acc[mf][nf], 0, 0, 0);
    __builtin_amdgcn_s_setprio(0);
    __builtin_amdgcn_sched_barrier(0);  // pin: A1 reads stay below MFMA-1

    // kk1 A reads (reuse af registers; WAR resolved by fence above)
#pragma unroll
    for (int mf = 0; mf < 8; ++mf) af[mf] = RD(base + aoff1 + mf * 2048);
    asm volatile("s_waitcnt lgkmcnt(0)" ::: "memory");
    __builtin_amdgcn_sched_barrier(0);
    __builtin_amdgcn_s_setprio(1);
#pragma unroll
    for (int mf = 0; mf < 8; ++mf)
#pragma unroll
      for (int nf = 0; nf < 4; ++nf)
        acc[mf][nf] = __builtin_amdgcn_mfma_f32_16x16x32_bf16(
            af[mf], bfr1[nf], acc[mf][nf], 0, 0, 0);
    __builtin_amdgcn_s_setprio(0);
    __builtin_amdgcn_sched_barrier(0);

    // boundary: stage(t+1) (only outstanding vmem) resident for all waves
    asm volatile("s_waitcnt vmcnt(0)" ::: "memory");
    GBARRIER();
  }

  // ------------- epilogue (R10 structure): + bias + inter @ B[slot] -------------
  const int slot = idx[m0 >> 11];  // block spans one batch (256 | 2048)
  const float* __restrict__ Bmat = loraB + (size_t)slot * RANK * N_TOT;
  const int gn0 = n0 + wc * 64 + rl;

  float bcv[4][RANK];
  float bv[4];
#pragma unroll
  for (int nf = 0; nf < 4; ++nf) {
    const int gn = gn0 + nf * 16;
    bv[nf] = bias[gn];
#pragma unroll
    for (int p = 0; p < RANK; ++p) bcv[nf][p] = Bmat[(size_t)p * N_TOT + gn];
  }
#pragma unroll
  for (int mf = 0; mf < 8; ++mf) {
    const int gmb = m0 + wr * 128 + mf * 16 + (q << 2);
#pragma unroll
    for (int r = 0; r < 4; ++r) {
      const int gm = gmb + r;
      const float4* ivp = reinterpret_cast<const float4*>(inter + (size_t)gm * RANK);
      const float4 iv0 = ivp[0], iv1 = ivp[1], iv2 = ivp[2], iv3 = ivp[3];
      float* orow = out + (size_t)gm * N_TOT;
#pragma unroll
      for (int nf = 0; nf < 4; ++nf) {
        const float lora =
            iv0.x * bcv[nf][0]  + iv0.y * bcv[nf][1]  + iv0.z * bcv[nf][2]  + iv0.w * bcv[nf][3] +
            iv1.x * bcv[nf][4]  + iv1.y * bcv[nf][5]  + iv1.z * bcv[nf][6]  + iv1.w * bcv[nf][7] +
            iv2.x * bcv[nf][8]  + iv2.y * bcv[nf][9]  + iv2.z * bcv[nf][10] + iv2.w * bcv[nf][11] +
            iv3.x * bcv[nf][12] + iv3.y * bcv[nf][13] + iv3.z * bcv[nf][14] + iv3.w * bcv[nf][15];
        orow[gn0 + nf * 16] = acc[mf][nf][r] + bv[nf] + lora;
      }
    }
  }
#undef STAGE64
}

// ---------------- host launcher ----------------
extern "C" void kernel_launch(void* const* d_in, const int* in_sizes, int n_in,
                              void* d_out, int out_size, void* d_ws, size_t ws_size,
                              hipStream_t stream) {
  const float* x     = (const float*)d_in[0];  // [8,2048,4096]
  const float* w     = (const float*)d_in[1];  // [4096,4096]
  const float* bias  = (const float*)d_in[2];  // [4096]
  const float* loraA = (const float*)d_in[3];  // [32,4096,16]
  const float* loraB = (const float*)d_in[4];  // [32,16,4096]
  const int*   idx   = (const int*)d_in[5];    // [8]
  float* out = (float*)d_out;

  char* ws = (char*)d_ws;
  unsigned short* xb   = (unsigned short*)ws;                  // 134,217,728 B
  unsigned short* wbuf = (unsigned short*)(ws + 134217728);    //  33,554,432 B
  float* inter = (float*)(ws + 134217728 + 33554432);          //   1,048,576 B

  fused_xcvt_inter_kernel<<<M_TOT / 16, 256, 0, stream>>>(x, loraA, idx, xb, inter);
  cvt_bf16_kernel<<<1024, 256, 0, stream>>>(w, wbuf, N_TOT * K_TOT / 4);
  gemm_fused_kernel<<<(M_TOT / 256) * (N_TOT / 256), 512, 0, stream>>>(
      xb, wbuf, bias, inter, loraB, idx, out);
}